// Round 7
// baseline (429.708 us; speedup 1.0000x reference)
//
#include <hip/hip_runtime.h>
#include <stdint.h>

// Problem constants
#define NDM   1024   // D_MODEL
#define NDS   16     // D_STATE
#define NDC   4      // D_CONV
#define NDI   2048   // D_INNER
#define NB    2      // BATCH
#define NL    2048   // SEQ
#define MROWS (NB*NL)   // 4096
#define CCH   32     // scan chunks  (scratch = NB*NDI*CCH*NDS*4 = 8.39MB each)
#define CLEN  64     // NL / CCH

typedef __bf16 bf16x8 __attribute__((ext_vector_type(8)));
typedef float  f32x4  __attribute__((ext_vector_type(4)));

__device__ __forceinline__ short f2bf(float f) {
  union { float f; unsigned u; } x; x.f = f;
  unsigned r = (x.u + 0x7FFFu + ((x.u >> 16) & 1u)) >> 16;
  return (short)r;
}

__device__ __forceinline__ void gload16(const void* g, void* l) {
  __builtin_amdgcn_global_load_lds(
      (__attribute__((address_space(1))) void*)(uintptr_t)g,
      (__attribute__((address_space(3))) void*)l,
      16, 0, 0);
}

// ---------------------------------------------------------------------------
// f32 -> bf16 elementwise convert
__global__ __launch_bounds__(256) void cvt_bf16_kernel(
    const float* __restrict__ in, short* __restrict__ out, int n) {
  int i = blockIdx.x * 256 + threadIdx.x;
  if (i < n) out[i] = f2bf(in[i]);
}

// ---------------------------------------------------------------------------
// (K,N) f32  ->  (N,K) bf16 transpose (32x32 LDS tiles)
__global__ __launch_bounds__(256) void transpose_bf16_kernel(
    const float* __restrict__ in, short* __restrict__ out, int K, int N) {
  __shared__ float t[32][33];
  const int tx = threadIdx.x, ty = threadIdx.y;   // 32, 8
  const int n0 = blockIdx.x * 32, k0 = blockIdx.y * 32;
  #pragma unroll
  for (int i = 0; i < 32; i += 8)
    t[ty + i][tx] = in[(size_t)(k0 + ty + i) * N + n0 + tx];
  __syncthreads();
  #pragma unroll
  for (int i = 0; i < 32; i += 8)
    out[(size_t)(n0 + ty + i) * K + k0 + tx] = f2bf(t[tx][ty + i]);
}

// ---------------------------------------------------------------------------
// Phase-pipelined bf16 TN GEMM: C(MxN,f32) = A(MxK,bf16)*Bt(NxK,bf16)^T + bias
// EPI: 0 = bias only, 1 = softplus(v + bias)
// 128x128 tile, 4 waves (2x2, per-wave 64x64 = 4x4 frags of 16x16x32).
// Ring of FOUR BK=32 half-tile buffers, depth-3 prefetch, counted vmcnt(8)
// (never drains to 0 until the last two tiles), ONE s_barrier per half-tile,
// stage issued right after the barrier, setprio(1) around the MFMA cluster.
// Waves skew between barriers (lgkmcnt-only deps) so one wave's MFMA overlaps
// another wave's ds_read burst -> no lockstep convoy.
template<int EPI>
__global__ __launch_bounds__(256, 2) void gemm_pipe_kernel(
    const short* __restrict__ A, const short* __restrict__ Bt,
    const float* __restrict__ bias, float* __restrict__ C,
    int M, int N, int K)
{
  const int tid  = threadIdx.x;
  const int lane = tid & 63;
  const int w    = tid >> 6;      // wave 0..3
  const int wM   = w >> 1;        // 0..1
  const int wN   = w & 1;         // 0..1
  const int g    = lane >> 4;     // k-group 0..3
  const int r    = lane & 15;     // row/col within fragment

  const int bm = blockIdx.y * 128;
  const int bn = blockIdx.x * 128;

  // fragment-major: slot R (16-row group 0..7) = 512 shorts (1KB);
  // element = R*512 + lane*8.  Wave w stages slots {w, w+4} of A and of B.
  __shared__ short sA[4][4096];   // 4 ring bufs x 8KB
  __shared__ short sB[4][4096];

  f32x4 acc[4][4];
  #pragma unroll
  for (int m = 0; m < 4; ++m)
    #pragma unroll
    for (int n = 0; n < 4; ++n)
      acc[m][n] = (f32x4){0.f, 0.f, 0.f, 0.f};

  const short* gA0 = A  + (size_t)(bm + w * 16 + r) * K + g * 8;
  const short* gA1 = A  + (size_t)(bm + (w + 4) * 16 + r) * K + g * 8;
  const short* gB0 = Bt + (size_t)(bn + w * 16 + r) * K + g * 8;
  const short* gB1 = Bt + (size_t)(bn + (w + 4) * 16 + r) * K + g * 8;

#define STAGE(buf, kb)                                          \
  do {                                                          \
    gload16(gA0 + (kb), &sA[buf][ w      * 512 + lane * 8]);    \
    gload16(gA1 + (kb), &sA[buf][(w + 4) * 512 + lane * 8]);    \
    gload16(gB0 + (kb), &sB[buf][ w      * 512 + lane * 8]);    \
    gload16(gB1 + (kb), &sB[buf][(w + 4) * 512 + lane * 8]);    \
  } while (0)

#define COMPUTE(cb)                                                           \
  do {                                                                        \
    bf16x8 af[4], bfv[4];                                                     \
    _Pragma("unroll")                                                         \
    for (int m = 0; m < 4; ++m)                                               \
      af[m] = *(const bf16x8*)&sA[cb][(wM * 4 + m) * 512 + lane * 8];         \
    _Pragma("unroll")                                                         \
    for (int n = 0; n < 4; ++n)                                               \
      bfv[n] = *(const bf16x8*)&sB[cb][(wN * 4 + n) * 512 + lane * 8];        \
    __builtin_amdgcn_s_setprio(1);                                            \
    _Pragma("unroll")                                                         \
    for (int m = 0; m < 4; ++m)                                               \
      _Pragma("unroll")                                                       \
      for (int n = 0; n < 4; ++n)                                             \
        acc[m][n] = __builtin_amdgcn_mfma_f32_16x16x32_bf16(                  \
            af[m], bfv[n], acc[m][n], 0, 0, 0);                               \
    __builtin_amdgcn_s_setprio(0);                                            \
  } while (0)

  const int NH = K >> 5;          // number of BK=32 half-tiles (>= 32 here)
  STAGE(0, 0);
  STAGE(1, 32);
  STAGE(2, 64);

  for (int h = 0; h < NH - 2; ++h) {
    asm volatile("s_waitcnt vmcnt(8)" ::: "memory");  // tile h's 4 loads done
    __builtin_amdgcn_s_barrier();                     // publish to all waves
    __builtin_amdgcn_sched_barrier(0);
    if (h + 3 < NH) STAGE((h + 3) & 3, (h + 3) * 32); // refill ring slot
    COMPUTE(h & 3);
  }
  // tail: h = NH-2 (8 outstanding -> wait 4), h = NH-1 (4 -> wait 0)
  asm volatile("s_waitcnt vmcnt(4)" ::: "memory");
  __builtin_amdgcn_s_barrier();
  __builtin_amdgcn_sched_barrier(0);
  COMPUTE((NH - 2) & 3);
  asm volatile("s_waitcnt vmcnt(0)" ::: "memory");
  __builtin_amdgcn_s_barrier();
  __builtin_amdgcn_sched_barrier(0);
  COMPUTE((NH - 1) & 3);
#undef STAGE
#undef COMPUTE

  // D layout (verified m89/m91): col = lane&15, row = (lane>>4)*4 + e
  #pragma unroll
  for (int m = 0; m < 4; ++m) {
    const int row0 = bm + wM * 64 + m * 16 + g * 4;
    #pragma unroll
    for (int n = 0; n < 4; ++n) {
      const int col = bn + wN * 64 + n * 16 + r;
      const float bv = bias[col];
      #pragma unroll
      for (int e = 0; e < 4; ++e) {
        float v = acc[m][n][e] + bv;
        if (EPI == 1) v = (v > 15.f) ? v : log1pf(__expf(v));
        C[(size_t)(row0 + e) * N + col] = v;
      }
    }
  }
}

// ---------------------------------------------------------------------------
// depthwise causal conv (width 4) + bias + SiLU; writes f32 and bf16 copies
__global__ __launch_bounds__(256) void conv_silu_kernel(
    const float* __restrict__ xz, const float* __restrict__ cw,
    const float* __restrict__ cb, float* __restrict__ xh,
    short* __restrict__ xhbf) {
  int idx = blockIdx.x * 256 + threadIdx.x;      // (b,t,c) over 2*2048*2048
  int c = idx & (NDI - 1);
  int t = (idx >> 11) & (NL - 1);
  int b = idx >> 22;
  const float* base = xz + ((size_t)b * NL) * (2 * NDI);
  float acc = cb[c];
  #pragma unroll
  for (int k = 0; k < NDC; ++k) {
    int tt = t - (NDC - 1) + k;
    if (tt >= 0) acc += cw[c * NDC + k] * base[(size_t)tt * (2 * NDI) + c];
  }
  float s = acc / (1.f + __expf(-acc));
  xh[idx] = s;
  xhbf[idx] = f2bf(s);
}

// ---------------------------------------------------------------------------
// Bmat[row, s] = sum_c xh[row,c] * W_x[c, 16+s] + b_x[16+s]; one wave per row
__global__ __launch_bounds__(256) void bmat_kernel(
    const float* __restrict__ xh, const float* __restrict__ Wx,
    const float* __restrict__ bx, float* __restrict__ Bm) {
  const int row  = blockIdx.x * 4 + (threadIdx.x >> 6);
  const int lane = threadIdx.x & 63;
  const int s = lane & 15, q = lane >> 4;
  const float* xr = xh + (size_t)row * NDI;
  float acc = 0.f;
  for (int c = q * 512; c < (q + 1) * 512; ++c)
    acc += xr[c] * Wx[c * (2 * NDS) + NDS + s];
  acc += __shfl_xor(acc, 16);
  acc += __shfl_xor(acc, 32);
  if (lane < 16) Bm[(size_t)row * NDS + s] = acc + bx[NDS + s];
}

// ---------------------------------------------------------------------------
// Chunked selective scan, phase 1: thread = (b, c, chunk); all 16 states in
// registers. Computes P_s = prod(dA_s) and hend_s (local scan, h_in = 0).
__global__ __launch_bounds__(256) void scan_p1_kernel(
    const float* __restrict__ delta, const float* __restrict__ Bm,
    const float* __restrict__ xh, const float* __restrict__ A_log,
    float* __restrict__ Pbuf, float* __restrict__ Hend) {
  const int i = blockIdx.x * 256 + threadIdx.x;     // NB*CCH*NDI
  const int c = i & (NDI - 1);
  const int k = (i >> 11) & (CCH - 1);
  const int b = i >> 16;                            // 11 + 5 bits
  const int t0 = k * CLEN;

  float Av[NDS];
  #pragma unroll
  for (int s = 0; s < NDS; ++s) Av[s] = -__expf(A_log[c * NDS + s]);

  const float* dp = delta + ((size_t)(b * NL + t0)) * NDI + c;
  const float* up = xh    + ((size_t)(b * NL + t0)) * NDI + c;
  const f32x4* Bp = (const f32x4*)(Bm + ((size_t)(b * NL + t0)) * NDS);

  float h[NDS], P[NDS];
  #pragma unroll
  for (int s = 0; s < NDS; ++s) { h[s] = 0.f; P[s] = 1.f; }

  #pragma unroll 4
  for (int j = 0; j < CLEN; ++j) {
    const float d = dp[(size_t)j * NDI];
    const float u = up[(size_t)j * NDI];
    f32x4 B0 = Bp[j * 4 + 0], B1 = Bp[j * 4 + 1];
    f32x4 B2 = Bp[j * 4 + 2], B3 = Bp[j * 4 + 3];
    const float du = d * u;
    float Bv[NDS];
    #pragma unroll
    for (int e = 0; e < 4; ++e) {
      Bv[e] = B0[e]; Bv[4 + e] = B1[e]; Bv[8 + e] = B2[e]; Bv[12 + e] = B3[e];
    }
    #pragma unroll
    for (int s = 0; s < NDS; ++s) {
      float dA = __expf(d * Av[s]);
      h[s] = dA * h[s] + du * Bv[s];
      P[s] *= dA;
    }
  }

  const size_t base = (((size_t)b * NDI + c) * CCH + k) * NDS;
  #pragma unroll
  for (int q = 0; q < 4; ++q) {
    *(f32x4*)&Pbuf[base + q * 4] = (f32x4){P[q*4], P[q*4+1], P[q*4+2], P[q*4+3]};
    *(f32x4*)&Hend[base + q * 4] = (f32x4){h[q*4], h[q*4+1], h[q*4+2], h[q*4+3]};
  }
}

// ---------------------------------------------------------------------------
// phase 2: thread = (b, c, s); serial combine across the chunks.
__global__ __launch_bounds__(256) void scan_p2_kernel(
    const float* __restrict__ Pbuf, const float* __restrict__ Hend,
    float* __restrict__ Hin) {
  const int i = blockIdx.x * 256 + threadIdx.x;     // 65536
  const int s = i & (NDS - 1);
  const int c = (i >> 4) & (NDI - 1);
  const int b = i >> 15;
  const size_t base = ((size_t)b * NDI + c) * CCH * NDS + s;
  float h = 0.f;
  #pragma unroll 8
  for (int k = 0; k < CCH; ++k) {
    Hin[base + (size_t)k * NDS] = h;
    h = Hend[base + (size_t)k * NDS] + Pbuf[base + (size_t)k * NDS] * h;
  }
}

// ---------------------------------------------------------------------------
// phase 3 + merge: rescan from h_in; y = (sum_s h + u*D) * silu(z) -> bf16
__global__ __launch_bounds__(256) void scan_p3_kernel(
    const float* __restrict__ delta, const float* __restrict__ Bm,
    const float* __restrict__ xh, const float* __restrict__ A_log,
    const float* __restrict__ Hin, const float* __restrict__ Dvec,
    const float* __restrict__ xz, short* __restrict__ ybf) {
  const int i = blockIdx.x * 256 + threadIdx.x;
  const int c = i & (NDI - 1);
  const int k = (i >> 11) & (CCH - 1);
  const int b = i >> 16;
  const int t0 = k * CLEN;

  float Av[NDS];
  #pragma unroll
  for (int s = 0; s < NDS; ++s) Av[s] = -__expf(A_log[c * NDS + s]);
  const float dcoef = Dvec[c];

  const float* dp = delta + ((size_t)(b * NL + t0)) * NDI + c;
  const float* up = xh    + ((size_t)(b * NL + t0)) * NDI + c;
  const f32x4* Bp = (const f32x4*)(Bm + ((size_t)(b * NL + t0)) * NDS);
  const float* zp = xz    + ((size_t)(b * NL + t0)) * (2 * NDI) + NDI + c;
  short* yp       = ybf   + ((size_t)(b * NL + t0)) * NDI + c;

  const size_t base = (((size_t)b * NDI + c) * CCH + k) * NDS;
  float h[NDS];
  #pragma unroll
  for (int s = 0; s < NDS; ++s) h[s] = Hin[base + s];

  #pragma unroll 4
  for (int j = 0; j < CLEN; ++j) {
    const float d = dp[(size_t)j * NDI];
    const float u = up[(size_t)j * NDI];
    f32x4 B0 = Bp[j * 4 + 0], B1 = Bp[j * 4 + 1];
    f32x4 B2 = Bp[j * 4 + 2], B3 = Bp[j * 4 + 3];
    const float du = d * u;
    float Bv[NDS];
    #pragma unroll
    for (int e = 0; e < 4; ++e) {
      Bv[e] = B0[e]; Bv[4 + e] = B1[e]; Bv[8 + e] = B2[e]; Bv[12 + e] = B3[e];
    }
    #pragma unroll
    for (int s = 0; s < NDS; ++s) {
      float dA = __expf(d * Av[s]);
      h[s] = dA * h[s] + du * Bv[s];
    }
    // register add-tree over the 16 states
    float sum01 = 0.f, sum23 = 0.f;
    #pragma unroll
    for (int s = 0; s < 8; ++s)  sum01 += h[s];
    #pragma unroll
    for (int s = 8; s < 16; ++s) sum23 += h[s];
    float y = sum01 + sum23 + u * dcoef;
    float z = zp[(size_t)j * (2 * NDI)];
    y *= z / (1.f + __expf(-z));
    yp[(size_t)j * NDI] = f2bf(y);
  }
}

// ---------------------------------------------------------------------------
extern "C" void kernel_launch(void* const* d_in, const int* in_sizes, int n_in,
                              void* d_out, int out_size, void* d_ws, size_t ws_size,
                              hipStream_t stream) {
  const float* x      = (const float*)d_in[0];
  const float* W_in   = (const float*)d_in[1];
  const float* b_in   = (const float*)d_in[2];
  const float* conv_w = (const float*)d_in[3];
  const float* conv_b = (const float*)d_in[4];
  const float* W_x    = (const float*)d_in[5];
  const float* b_x    = (const float*)d_in[6];
  const float* W_dt   = (const float*)d_in[7];
  const float* b_dt   = (const float*)d_in[8];
  const float* A_log  = (const float*)d_in[9];
  const float* Dv     = (const float*)d_in[10];
  const float* W_out  = (const float*)d_in[11];
  const float* b_out  = (const float*)d_in[12];
  float* out = (float*)d_out;

  char* w = (char*)d_ws;
  short* xbf   = (short*)(w);                  // 4096x1024 bf16   8.39MB
  short* WtIn  = (short*)(w + 8388608);        // 4096x1024 bf16   8.39MB
  short* WtDt  = (short*)(w + 16777216);       // 2048x2048 bf16   8.39MB
  short* WtOut = (short*)(w + 25165824);       // 1024x2048 bf16   4.19MB
  float* xz    = (float*)(w + 29360128);       // 4096x4096 f32   67.1MB
  float* xhf   = (float*)(w + 96468992);       // 4096x2048 f32   33.6MB
  short* xhbf  = (short*)(w + 130023424);      // 4096x2048 bf16  16.8MB
  float* delta = (float*)(w + 146800640);      // 4096x2048 f32   33.6MB
  float* Bm    = (float*)(w + 180355072);      // 4096x16   f32    0.26MB
  short* ybf   = (short*)(w + 214171648);      // 4096x2048 bf16  16.8MB
  // scan scratch aliases buffers that are dead by scan time.
  float* Pbuf  = (float*)(w);                  // aliases xbf  (8.39MB)
  float* Hend  = (float*)(w + 8388608);        // aliases WtIn (8.39MB)
  float* Hin   = (float*)(w + 16777216);       // aliases WtDt (8.39MB)

  // 1) converts / weight transposes (K,N)->(N,K) bf16
  cvt_bf16_kernel<<<(MROWS * NDM) / 256, 256, 0, stream>>>(x, xbf, MROWS * NDM);
  transpose_bf16_kernel<<<dim3((2 * NDI) / 32, NDM / 32), dim3(32, 8), 0, stream>>>(
      W_in, WtIn, NDM, 2 * NDI);
  transpose_bf16_kernel<<<dim3(NDI / 32, NDI / 32), dim3(32, 8), 0, stream>>>(
      W_dt, WtDt, NDI, NDI);
  transpose_bf16_kernel<<<dim3(NDM / 32, NDI / 32), dim3(32, 8), 0, stream>>>(
      W_out, WtOut, NDI, NDM);

  // 2) xz = x @ W_in + b_in   (32x32 = 1024 blocks)
  gemm_pipe_kernel<0><<<dim3((2 * NDI) / 128, MROWS / 128), 256, 0, stream>>>(
      xbf, WtIn, b_in, xz, MROWS, 2 * NDI, NDM);

  // 3) depthwise conv + silu
  conv_silu_kernel<<<(MROWS * NDI) / 256, 256, 0, stream>>>(
      xz, conv_w, conv_b, xhf, xhbf);

  // 4) Bmat = xh @ W_x[:,16:32] + b_x[16:32]
  bmat_kernel<<<MROWS / 4, 256, 0, stream>>>(xhf, W_x, b_x, Bm);

  // 5) delta = softplus(xh @ W_dt + b_dt)   (16x32 = 512 blocks)
  gemm_pipe_kernel<1><<<dim3(NDI / 128, MROWS / 128), 256, 0, stream>>>(
      xhbf, WtDt, b_dt, delta, MROWS, NDI, NDI);

  // 6) selective scan (chunked: local scan -> chunk combine -> rescan+merge)
  scan_p1_kernel<<<(NB * NDI * CCH) / 256, 256, 0, stream>>>(
      delta, Bm, xhf, A_log, Pbuf, Hend);
  scan_p2_kernel<<<(NB * NDI * NDS) / 256, 256, 0, stream>>>(Pbuf, Hend, Hin);
  scan_p3_kernel<<<(NB * NDI * CCH) / 256, 256, 0, stream>>>(
      delta, Bm, xhf, A_log, Hin, Dv, xz, ybf);

  // 7) out = y @ W_out + b_out   (8x32 = 256 blocks)
  gemm_pipe_kernel<0><<<dim3(NDM / 128, MROWS / 128), 256, 0, stream>>>(
      ybf, WtOut, b_out, out, MROWS, NDM, NDI);
}

// Round 8
// 378.980 us; speedup vs baseline: 1.1339x; 1.1339x over previous
//
#include <hip/hip_runtime.h>
#include <stdint.h>

// Problem constants
#define NDM   1024   // D_MODEL
#define NDS   16     // D_STATE
#define NDC   4      // D_CONV
#define NDI   2048   // D_INNER
#define NB    2      // BATCH
#define NL    2048   // SEQ
#define MROWS (NB*NL)   // 4096
#define CCH   32     // scan chunks  (scratch = NB*NDI*CCH*NDS*4 = 8.39MB each)
#define CLEN  64     // NL / CCH

typedef __bf16 bf16x8 __attribute__((ext_vector_type(8)));
typedef float  f32x4  __attribute__((ext_vector_type(4)));
typedef short  short8 __attribute__((ext_vector_type(8)));

__device__ __forceinline__ short f2bf(float f) {
  union { float f; unsigned u; } x; x.f = f;
  unsigned r = (x.u + 0x7FFFu + ((x.u >> 16) & 1u)) >> 16;
  return (short)r;
}

__device__ __forceinline__ void gload16(const void* g, void* l) {
  __builtin_amdgcn_global_load_lds(
      (__attribute__((address_space(1))) void*)(uintptr_t)g,
      (__attribute__((address_space(3))) void*)l,
      16, 0, 0);
}

// Fragment-order Global layout (FG) for a logical row-major (R x K) bf16
// matrix: 16-row groups; within a group, chunk (k8, r) of 8 shorts at
// k8*128 + r*8. A 16x32 MFMA fragment (4 consecutive k8 x 16 rows) is a
// CONTIGUOUS 1KB block in lane order -> global_load_lds is fully coalesced
// and LDS reads are lane*16 linear (conflict-free).
__device__ __forceinline__ size_t fgoff(int row, int k8, int K) {
  return (size_t)(row >> 4) * K * 16 + (size_t)k8 * 128 + (row & 15) * 8;
}

// ---------------------------------------------------------------------------
// x (f32, MROWS x 1024 row-major) -> FG bf16.  Coalesced 32B reads,
// scattered 16B writes (absorbed by L2).
__global__ __launch_bounds__(256) void cvt_fg_kernel(
    const float* __restrict__ in, short* __restrict__ out) {
  int j = blockIdx.x * 256 + threadIdx.x;      // chunk id, K8 = 128
  int row = j >> 7, k8 = j & 127;
  const float* p = in + (size_t)row * 1024 + k8 * 8;
  short8 v;
  #pragma unroll
  for (int e = 0; e < 8; ++e) v[e] = f2bf(p[e]);
  *(short8*)&out[fgoff(row, k8, 1024)] = v;
}

// ---------------------------------------------------------------------------
// W (K x N f32) -> FG bf16 of W^T (N rows, K cols). 32n x 64k tiles.
__global__ __launch_bounds__(256) void transpose_fg_kernel(
    const float* __restrict__ in, short* __restrict__ out, int K, int N) {
  __shared__ float t[64][33];
  const int tx = threadIdx.x, ty = threadIdx.y;   // 32, 8
  const int n0 = blockIdx.x * 32, k0 = blockIdx.y * 64;
  #pragma unroll
  for (int i = 0; i < 64; i += 8)
    t[ty + i][tx] = in[(size_t)(k0 + ty + i) * N + n0 + tx];
  __syncthreads();
  const int n = n0 + tx, k8 = (k0 >> 3) + ty;
  short8 v;
  #pragma unroll
  for (int e = 0; e < 8; ++e) v[e] = f2bf(t[ty * 8 + e][tx]);
  *(short8*)&out[fgoff(n, k8, K)] = v;
}

// ---------------------------------------------------------------------------
// FG bf16 TN GEMM: C(MxN,f32) = A_fg(MxK) * B_fg(NxK)^T + bias
// EPI: 0 = bias only, 1 = softplus(v + bias)
// 128x128 tile, BK=64, 4 waves (2x2, per-wave 64x64), LDS double-buffer.
// Staging: 16 fully-coalesced 1KB global_load_lds per half-K-step side.
template<int EPI>
__global__ __launch_bounds__(256, 2) void gemm_fg_kernel(
    const short* __restrict__ A, const short* __restrict__ Bt,
    const float* __restrict__ bias, float* __restrict__ C,
    int M, int N, int K)
{
  const int tid  = threadIdx.x;
  const int lane = tid & 63;
  const int w    = tid >> 6;      // wave 0..3
  const int wM   = w >> 1;
  const int wN   = w & 1;
  const int g    = lane >> 4;
  const int r    = lane & 15;

  const int bm = blockIdx.y * 128;
  const int bn = blockIdx.x * 128;

  // LDS slot (R=row-group 0..7, kk 0..1) = 1KB at (R*2+kk)*512 shorts
  __shared__ short sA[2][8192];
  __shared__ short sB[2][8192];

  f32x4 acc[4][4];
  #pragma unroll
  for (int m = 0; m < 4; ++m)
    #pragma unroll
    for (int n = 0; n < 4; ++n)
      acc[m][n] = (f32x4){0.f, 0.f, 0.f, 0.f};

  // wave w stages row-groups R = w*2, w*2+1 of both A and B.
  // FG frag base (shorts): group*(K*16) + (kb + kk*32)*16 ; per-lane +lane*8.
  const short* pA[2];
  const short* pB[2];
  #pragma unroll
  for (int q = 0; q < 2; ++q) {
    pA[q] = A  + (size_t)((bm >> 4) + w * 2 + q) * K * 16 + lane * 8;
    pB[q] = Bt + (size_t)((bn >> 4) + w * 2 + q) * K * 16 + lane * 8;
  }

#define STAGE(buf, kb)                                                       \
  do {                                                                       \
    _Pragma("unroll")                                                        \
    for (int q = 0; q < 2; ++q)                                              \
      _Pragma("unroll")                                                      \
      for (int kk = 0; kk < 2; ++kk) {                                       \
        gload16(pA[q] + (size_t)(kb) * 16 + kk * 512,                        \
                &sA[buf][((w * 2 + q) * 2 + kk) * 512]);                     \
        gload16(pB[q] + (size_t)(kb) * 16 + kk * 512,                        \
                &sB[buf][((w * 2 + q) * 2 + kk) * 512]);                     \
      }                                                                      \
  } while (0)

  STAGE(0, 0);
  int cur = 0;
  for (int kb = 0; kb < K; kb += 64) {
    __syncthreads();                 // stages into cur visible; prev buf free
    if (kb + 64 < K) STAGE(cur ^ 1, kb + 64);   // prefetch under compute

    bf16x8 af[4][2], bfv[4][2];
    #pragma unroll
    for (int m = 0; m < 4; ++m)
      #pragma unroll
      for (int kk = 0; kk < 2; ++kk)
        af[m][kk] = *(const bf16x8*)&sA[cur][((wM * 4 + m) * 2 + kk) * 512 + lane * 8];
    #pragma unroll
    for (int n = 0; n < 4; ++n)
      #pragma unroll
      for (int kk = 0; kk < 2; ++kk)
        bfv[n][kk] = *(const bf16x8*)&sB[cur][((wN * 4 + n) * 2 + kk) * 512 + lane * 8];

    #pragma unroll
    for (int kk = 0; kk < 2; ++kk)
      #pragma unroll
      for (int m = 0; m < 4; ++m)
        #pragma unroll
        for (int n = 0; n < 4; ++n)
          acc[m][n] = __builtin_amdgcn_mfma_f32_16x16x32_bf16(
              af[m][kk], bfv[n][kk], acc[m][n], 0, 0, 0);
    cur ^= 1;
  }
#undef STAGE

  // D layout (verified m89/m91): col = lane&15, row = (lane>>4)*4 + e
  #pragma unroll
  for (int m = 0; m < 4; ++m) {
    const int row0 = bm + wM * 64 + m * 16 + g * 4;
    #pragma unroll
    for (int n = 0; n < 4; ++n) {
      const int col = bn + wN * 64 + n * 16 + r;
      const float bv = bias[col];
      #pragma unroll
      for (int e = 0; e < 4; ++e) {
        float v = acc[m][n][e] + bv;
        if (EPI == 1) v = (v > 15.f) ? v : log1pf(__expf(v));
        C[(size_t)(row0 + e) * N + col] = v;
      }
    }
  }
}

// ---------------------------------------------------------------------------
// depthwise causal conv (width 4) + bias + SiLU; one 8-channel chunk/thread.
// Writes xh f32 row-major (coalesced) and FG bf16 (16B scattered, L2-absorbed)
__global__ __launch_bounds__(256) void conv_silu_kernel(
    const float* __restrict__ xz, const float* __restrict__ cw,
    const float* __restrict__ cb, float* __restrict__ xh,
    short* __restrict__ xhbf) {
  int j = blockIdx.x * 256 + threadIdx.x;        // chunk id, K8 = 256
  int row = j >> 8, k8 = j & 255;
  int b = row >> 11, t = row & (NL - 1);
  int c0 = k8 * 8;
  const float* base = xz + ((size_t)b * NL) * (2 * NDI) + c0;
  float acc[8];
  #pragma unroll
  for (int e = 0; e < 8; ++e) acc[e] = cb[c0 + e];
  #pragma unroll
  for (int k = 0; k < NDC; ++k) {
    int tt = t - (NDC - 1) + k;
    if (tt >= 0) {
      const float* rp = base + (size_t)tt * (2 * NDI);
      #pragma unroll
      for (int e = 0; e < 8; ++e) acc[e] += cw[(c0 + e) * NDC + k] * rp[e];
    }
  }
  float* xo = xh + (size_t)row * NDI + c0;
  short8 v;
  #pragma unroll
  for (int e = 0; e < 8; ++e) {
    float s = acc[e] / (1.f + __expf(-acc[e]));
    xo[e] = s;
    v[e] = f2bf(s);
  }
  *(short8*)&xhbf[fgoff(row, k8, NDI)] = v;
}

// ---------------------------------------------------------------------------
// Bmat[row, s] = sum_c xh[row,c] * W_x[c, 16+s] + b_x[16+s]; one wave per row
__global__ __launch_bounds__(256) void bmat_kernel(
    const float* __restrict__ xh, const float* __restrict__ Wx,
    const float* __restrict__ bx, float* __restrict__ Bm) {
  const int row  = blockIdx.x * 4 + (threadIdx.x >> 6);
  const int lane = threadIdx.x & 63;
  const int s = lane & 15, q = lane >> 4;
  const float* xr = xh + (size_t)row * NDI;
  float acc = 0.f;
  for (int c = q * 512; c < (q + 1) * 512; ++c)
    acc += xr[c] * Wx[c * (2 * NDS) + NDS + s];
  acc += __shfl_xor(acc, 16);
  acc += __shfl_xor(acc, 32);
  if (lane < 16) Bm[(size_t)row * NDS + s] = acc + bx[NDS + s];
}

// ---------------------------------------------------------------------------
// scan scratch layout: [b][k][c][s] -> offset ((b*CCH+k)*NDI+c)*NDS+s
// (lane-contiguous for p1 writes, p2 reads, p3 reads)
__device__ __forceinline__ size_t scoff(int b, int k, int c) {
  return (((size_t)b * CCH + k) * NDI + c) * NDS;
}

// phase 1: thread = (b, c, chunk); 16 states in registers.
__global__ __launch_bounds__(256) void scan_p1_kernel(
    const float* __restrict__ delta, const float* __restrict__ Bm,
    const float* __restrict__ xh, const float* __restrict__ A_log,
    float* __restrict__ Pbuf, float* __restrict__ Hend) {
  const int i = blockIdx.x * 256 + threadIdx.x;     // NB*CCH*NDI
  const int c = i & (NDI - 1);
  const int k = (i >> 11) & (CCH - 1);
  const int b = i >> 16;
  const int t0 = k * CLEN;

  float Av[NDS];
  #pragma unroll
  for (int s = 0; s < NDS; ++s) Av[s] = -__expf(A_log[c * NDS + s]);

  const float* dp = delta + ((size_t)(b * NL + t0)) * NDI + c;
  const float* up = xh    + ((size_t)(b * NL + t0)) * NDI + c;
  const f32x4* Bp = (const f32x4*)(Bm + ((size_t)(b * NL + t0)) * NDS);

  float h[NDS], P[NDS];
  #pragma unroll
  for (int s = 0; s < NDS; ++s) { h[s] = 0.f; P[s] = 1.f; }

  #pragma unroll 4
  for (int j = 0; j < CLEN; ++j) {
    const float d = dp[(size_t)j * NDI];
    const float u = up[(size_t)j * NDI];
    f32x4 B0 = Bp[j * 4 + 0], B1 = Bp[j * 4 + 1];
    f32x4 B2 = Bp[j * 4 + 2], B3 = Bp[j * 4 + 3];
    const float du = d * u;
    float Bv[NDS];
    #pragma unroll
    for (int e = 0; e < 4; ++e) {
      Bv[e] = B0[e]; Bv[4 + e] = B1[e]; Bv[8 + e] = B2[e]; Bv[12 + e] = B3[e];
    }
    #pragma unroll
    for (int s = 0; s < NDS; ++s) {
      float dA = __expf(d * Av[s]);
      h[s] = dA * h[s] + du * Bv[s];
      P[s] *= dA;
    }
  }

  const size_t base = scoff(b, k, c);
  #pragma unroll
  for (int q = 0; q < 4; ++q) {
    *(f32x4*)&Pbuf[base + q * 4] = (f32x4){P[q*4], P[q*4+1], P[q*4+2], P[q*4+3]};
    *(f32x4*)&Hend[base + q * 4] = (f32x4){h[q*4], h[q*4+1], h[q*4+2], h[q*4+3]};
  }
}

// ---------------------------------------------------------------------------
// phase 2: thread = (b, c, s); serial combine across the chunks.
__global__ __launch_bounds__(256) void scan_p2_kernel(
    const float* __restrict__ Pbuf, const float* __restrict__ Hend,
    float* __restrict__ Hin) {
  const int i = blockIdx.x * 256 + threadIdx.x;     // 65536
  const int s = i & (NDS - 1);
  const int c = (i >> 4) & (NDI - 1);
  const int b = i >> 15;
  const size_t step = (size_t)NDI * NDS;
  const size_t base = scoff(b, 0, c) + s;
  float h = 0.f;
  #pragma unroll 8
  for (int k = 0; k < CCH; ++k) {
    Hin[base + (size_t)k * step] = h;
    h = Hend[base + (size_t)k * step] + Pbuf[base + (size_t)k * step] * h;
  }
}

// ---------------------------------------------------------------------------
// phase 3 + merge: rescan from h_in; y = (sum_s h + u*D) * silu(z);
// LDS slab-transpose -> FG bf16 output (coalesced-ish 16B chunk writes).
__global__ __launch_bounds__(256) void scan_p3_kernel(
    const float* __restrict__ delta, const float* __restrict__ Bm,
    const float* __restrict__ xh, const float* __restrict__ A_log,
    const float* __restrict__ Hin, const float* __restrict__ Dvec,
    const float* __restrict__ xz, short* __restrict__ ybf) {
  const int tid = threadIdx.x;
  const int i = blockIdx.x * 256 + tid;
  const int c = i & (NDI - 1);
  const int k = (i >> 11) & (CCH - 1);
  const int b = i >> 16;
  const int t0 = k * CLEN;
  const int cb0 = (blockIdx.x * 256) & (NDI - 1);   // block's base channel

  __shared__ float ylds[16][258];

  float Av[NDS];
  #pragma unroll
  for (int s = 0; s < NDS; ++s) Av[s] = -__expf(A_log[c * NDS + s]);
  const float dcoef = Dvec[c];

  const float* dp = delta + ((size_t)(b * NL + t0)) * NDI + c;
  const float* up = xh    + ((size_t)(b * NL + t0)) * NDI + c;
  const f32x4* Bp = (const f32x4*)(Bm + ((size_t)(b * NL + t0)) * NDS);
  const float* zp = xz    + ((size_t)(b * NL + t0)) * (2 * NDI) + NDI + c;

  const size_t base = scoff(b, k, c);
  float h[NDS];
  #pragma unroll
  for (int s = 0; s < NDS; ++s) h[s] = Hin[base + s];

  for (int j = 0; j < CLEN; ++j) {
    const float d = dp[(size_t)j * NDI];
    const float u = up[(size_t)j * NDI];
    f32x4 B0 = Bp[j * 4 + 0], B1 = Bp[j * 4 + 1];
    f32x4 B2 = Bp[j * 4 + 2], B3 = Bp[j * 4 + 3];
    const float du = d * u;
    float Bv[NDS];
    #pragma unroll
    for (int e = 0; e < 4; ++e) {
      Bv[e] = B0[e]; Bv[4 + e] = B1[e]; Bv[8 + e] = B2[e]; Bv[12 + e] = B3[e];
    }
    #pragma unroll
    for (int s = 0; s < NDS; ++s) {
      float dA = __expf(d * Av[s]);
      h[s] = dA * h[s] + du * Bv[s];
    }
    float sum01 = 0.f, sum23 = 0.f;
    #pragma unroll
    for (int s = 0; s < 8; ++s)  sum01 += h[s];
    #pragma unroll
    for (int s = 8; s < 16; ++s) sum23 += h[s];
    float y = sum01 + sum23 + u * dcoef;
    float z = zp[(size_t)j * (2 * NDI)];
    y *= z / (1.f + __expf(-z));
    ylds[j & 15][tid] = y;

    if ((j & 15) == 15) {               // drain slab: 16 t x 256 c -> FG
      __syncthreads();
      const int jb = j - 15;
      #pragma unroll
      for (int s2 = 0; s2 < 2; ++s2) {
        int u2 = tid + 256 * s2;
        int tt = u2 >> 5, q = u2 & 31;
        short8 v;
        #pragma unroll
        for (int e = 0; e < 8; ++e) v[e] = f2bf(ylds[tt][q * 8 + e]);
        int grow = b * NL + t0 + jb + tt;
        int k8 = (cb0 >> 3) + q;
        *(short8*)&ybf[fgoff(grow, k8, NDI)] = v;
      }
      __syncthreads();
    }
  }
}

// ---------------------------------------------------------------------------
extern "C" void kernel_launch(void* const* d_in, const int* in_sizes, int n_in,
                              void* d_out, int out_size, void* d_ws, size_t ws_size,
                              hipStream_t stream) {
  const float* x      = (const float*)d_in[0];
  const float* W_in   = (const float*)d_in[1];
  const float* b_in   = (const float*)d_in[2];
  const float* conv_w = (const float*)d_in[3];
  const float* conv_b = (const float*)d_in[4];
  const float* W_x    = (const float*)d_in[5];
  const float* b_x    = (const float*)d_in[6];
  const float* W_dt   = (const float*)d_in[7];
  const float* b_dt   = (const float*)d_in[8];
  const float* A_log  = (const float*)d_in[9];
  const float* Dv     = (const float*)d_in[10];
  const float* W_out  = (const float*)d_in[11];
  const float* b_out  = (const float*)d_in[12];
  float* out = (float*)d_out;

  char* w = (char*)d_ws;
  short* xbf   = (short*)(w);                  // FG 4096x1024 bf16   8.39MB
  short* WtIn  = (short*)(w + 8388608);        // FG 4096x1024 bf16   8.39MB
  short* WtDt  = (short*)(w + 16777216);       // FG 2048x2048 bf16   8.39MB
  short* WtOut = (short*)(w + 25165824);       // FG 1024x2048 bf16   4.19MB
  float* xz    = (float*)(w + 29360128);       // 4096x4096 f32      67.1MB
  float* xhf   = (float*)(w + 96468992);       // 4096x2048 f32      33.6MB
  short* xhbf  = (short*)(w + 130023424);      // FG 4096x2048 bf16  16.8MB
  float* delta = (float*)(w + 146800640);      // 4096x2048 f32      33.6MB
  float* Bm    = (float*)(w + 180355072);      // 4096x16   f32       0.26MB
  short* ybf   = (short*)(w + 214171648);      // FG 4096x2048 bf16  16.8MB
  // scan scratch aliases buffers dead by scan time (8.39MB each, CCH=32):
  float* Pbuf  = (float*)(w);                  // aliases xbf
  float* Hend  = (float*)(w + 8388608);        // aliases WtIn
  float* Hin   = (float*)(w + 16777216);       // aliases WtDt

  // 1) converts / weight transposes into FG layout
  cvt_fg_kernel<<<(MROWS * NDM / 8) / 256, 256, 0, stream>>>(x, xbf);
  transpose_fg_kernel<<<dim3((2 * NDI) / 32, NDM / 64), dim3(32, 8), 0, stream>>>(
      W_in, WtIn, NDM, 2 * NDI);
  transpose_fg_kernel<<<dim3(NDI / 32, NDI / 64), dim3(32, 8), 0, stream>>>(
      W_dt, WtDt, NDI, NDI);
  transpose_fg_kernel<<<dim3(NDM / 32, NDI / 64), dim3(32, 8), 0, stream>>>(
      W_out, WtOut, NDI, NDM);

  // 2) xz = x @ W_in + b_in
  gemm_fg_kernel<0><<<dim3((2 * NDI) / 128, MROWS / 128), 256, 0, stream>>>(
      xbf, WtIn, b_in, xz, MROWS, 2 * NDI, NDM);

  // 3) depthwise conv + silu (writes xhf row-major + xhbf FG)
  conv_silu_kernel<<<(MROWS * NDI / 8) / 256, 256, 0, stream>>>(
      xz, conv_w, conv_b, xhf, xhbf);

  // 4) Bmat = xh @ W_x[:,16:32] + b_x[16:32]
  bmat_kernel<<<MROWS / 4, 256, 0, stream>>>(xhf, W_x, b_x, Bm);

  // 5) delta = softplus(xh @ W_dt + b_dt)
  gemm_fg_kernel<1><<<dim3(NDI / 128, MROWS / 128), 256, 0, stream>>>(
      xhbf, WtDt, b_dt, delta, MROWS, NDI, NDI);

  // 6) selective scan (chunked: local scan -> chunk combine -> rescan+merge)
  scan_p1_kernel<<<(NB * NDI * CCH) / 256, 256, 0, stream>>>(
      delta, Bm, xhf, A_log, Pbuf, Hend);
  scan_p2_kernel<<<(NB * NDI * NDS) / 256, 256, 0, stream>>>(Pbuf, Hend, Hin);
  scan_p3_kernel<<<(NB * NDI * CCH) / 256, 256, 0, stream>>>(
      delta, Bm, xhf, A_log, Hin, Dv, xz, ybf);

  // 7) out = y @ W_out + b_out
  gemm_fg_kernel<0><<<dim3(NDM / 128, MROWS / 128), 256, 0, stream>>>(
      ybf, WtOut, b_out, out, MROWS, NDM, NDI);
}

// Round 9
// 341.635 us; speedup vs baseline: 1.2578x; 1.1093x over previous
//
#include <hip/hip_runtime.h>
#include <stdint.h>

// Problem constants
#define NDM   1024   // D_MODEL
#define NDS   16     // D_STATE
#define NDC   4      // D_CONV
#define NDI   2048   // D_INNER
#define NB    2      // BATCH
#define NL    2048   // SEQ
#define MROWS (NB*NL)   // 4096
#define CCH   32     // scan chunks  (scratch = NB*NDI*CCH*NDS*4 = 8.39MB each)
#define CLEN  64     // NL / CCH

typedef __bf16 bf16x8 __attribute__((ext_vector_type(8)));
typedef float  f32x4  __attribute__((ext_vector_type(4)));
typedef short  short8 __attribute__((ext_vector_type(8)));

__device__ __forceinline__ short f2bf(float f) {
  union { float f; unsigned u; } x; x.f = f;
  unsigned r = (x.u + 0x7FFFu + ((x.u >> 16) & 1u)) >> 16;
  return (short)r;
}

__device__ __forceinline__ void gload16(const void* g, void* l) {
  __builtin_amdgcn_global_load_lds(
      (__attribute__((address_space(1))) void*)(uintptr_t)g,
      (__attribute__((address_space(3))) void*)l,
      16, 0, 0);
}

// Fragment-order Global layout (FG) for a logical row-major (R x K) bf16
// matrix: 16-row groups; chunk (k8, r) of 8 shorts at k8*128 + (r&15)*8.
// A 16x32 MFMA fragment is a CONTIGUOUS 1KB block in lane order.
__device__ __forceinline__ size_t fgoff(int row, int k8, int K) {
  return (size_t)(row >> 4) * K * 16 + (size_t)k8 * 128 + (row & 15) * 8;
}

// ---------------------------------------------------------------------------
// x (f32, MROWS x 1024 row-major) -> FG bf16 via LDS slab (coalesced both ways)
__global__ __launch_bounds__(256) void cvt_fg_kernel(
    const float* __restrict__ in, short* __restrict__ out) {
  __shared__ short slab[16][1032];         // stride 2064B = 16B-aligned
  const int tid = threadIdx.x;
  const int g = blockIdx.x;                // 16-row group
  const float* p = in + (size_t)g * 16 * 1024;
  #pragma unroll
  for (int u = 0; u < 8; ++u) {
    int unit = u * 256 + tid;              // 2048 = 16 rows x 128 chunks
    int rr = unit >> 7, cc = unit & 127;
    const float* rp = p + (size_t)rr * 1024 + cc * 8;
    #pragma unroll
    for (int e = 0; e < 8; ++e) slab[rr][cc * 8 + e] = f2bf(rp[e]);
  }
  __syncthreads();
  short* op = out + (size_t)g * 16384;     // whole group contiguous in FG
  #pragma unroll
  for (int u = 0; u < 8; ++u) {
    int u2 = u * 256 + tid;
    int rr = u2 & 15, k8 = u2 >> 4;        // rr-minor -> contiguous 16B chunks
    *(short8*)&op[k8 * 128 + rr * 8] = *(short8*)&slab[rr][k8 * 8];
  }
}

// ---------------------------------------------------------------------------
// W (K x N f32) -> FG bf16 of W^T (N rows, K cols). 32n x 64k tiles.
// (writes are 256B-contiguous runs of 16 threads -> full lines, OK as-is)
__global__ __launch_bounds__(256) void transpose_fg_kernel(
    const float* __restrict__ in, short* __restrict__ out, int K, int N) {
  __shared__ float t[64][33];
  const int tx = threadIdx.x, ty = threadIdx.y;   // 32, 8
  const int n0 = blockIdx.x * 32, k0 = blockIdx.y * 64;
  #pragma unroll
  for (int i = 0; i < 64; i += 8)
    t[ty + i][tx] = in[(size_t)(k0 + ty + i) * N + n0 + tx];
  __syncthreads();
  const int n = n0 + tx, k8 = (k0 >> 3) + ty;
  short8 v;
  #pragma unroll
  for (int e = 0; e < 8; ++e) v[e] = f2bf(t[ty * 8 + e][tx]);
  *(short8*)&out[fgoff(n, k8, K)] = v;
}

// ---------------------------------------------------------------------------
// FG bf16 TN GEMM: C(MxN,f32) = A_fg(MxK) * B_fg(NxK)^T + bias
// EPI: 0 = bias only, 1 = softplus(v + bias)
// 128x128 tile, BK=64, 4 waves (2x2, per-wave 64x64), LDS double-buffer.
template<int EPI>
__global__ __launch_bounds__(256, 2) void gemm_fg_kernel(
    const short* __restrict__ A, const short* __restrict__ Bt,
    const float* __restrict__ bias, float* __restrict__ C,
    int M, int N, int K)
{
  const int tid  = threadIdx.x;
  const int lane = tid & 63;
  const int w    = tid >> 6;      // wave 0..3
  const int wM   = w >> 1;
  const int wN   = w & 1;
  const int g    = lane >> 4;
  const int r    = lane & 15;

  const int bm = blockIdx.y * 128;
  const int bn = blockIdx.x * 128;

  __shared__ short sA[2][8192];
  __shared__ short sB[2][8192];

  f32x4 acc[4][4];
  #pragma unroll
  for (int m = 0; m < 4; ++m)
    #pragma unroll
    for (int n = 0; n < 4; ++n)
      acc[m][n] = (f32x4){0.f, 0.f, 0.f, 0.f};

  const short* pA[2];
  const short* pB[2];
  #pragma unroll
  for (int q = 0; q < 2; ++q) {
    pA[q] = A  + (size_t)((bm >> 4) + w * 2 + q) * K * 16 + lane * 8;
    pB[q] = Bt + (size_t)((bn >> 4) + w * 2 + q) * K * 16 + lane * 8;
  }

#define STAGE(buf, kb)                                                       \
  do {                                                                       \
    _Pragma("unroll")                                                        \
    for (int q = 0; q < 2; ++q)                                              \
      _Pragma("unroll")                                                      \
      for (int kk = 0; kk < 2; ++kk) {                                       \
        gload16(pA[q] + (size_t)(kb) * 16 + kk * 512,                        \
                &sA[buf][((w * 2 + q) * 2 + kk) * 512]);                     \
        gload16(pB[q] + (size_t)(kb) * 16 + kk * 512,                        \
                &sB[buf][((w * 2 + q) * 2 + kk) * 512]);                     \
      }                                                                      \
  } while (0)

  STAGE(0, 0);
  int cur = 0;
  for (int kb = 0; kb < K; kb += 64) {
    __syncthreads();
    if (kb + 64 < K) STAGE(cur ^ 1, kb + 64);

    bf16x8 af[4][2], bfv[4][2];
    #pragma unroll
    for (int m = 0; m < 4; ++m)
      #pragma unroll
      for (int kk = 0; kk < 2; ++kk)
        af[m][kk] = *(const bf16x8*)&sA[cur][((wM * 4 + m) * 2 + kk) * 512 + lane * 8];
    #pragma unroll
    for (int n = 0; n < 4; ++n)
      #pragma unroll
      for (int kk = 0; kk < 2; ++kk)
        bfv[n][kk] = *(const bf16x8*)&sB[cur][((wN * 4 + n) * 2 + kk) * 512 + lane * 8];

    #pragma unroll
    for (int kk = 0; kk < 2; ++kk)
      #pragma unroll
      for (int m = 0; m < 4; ++m)
        #pragma unroll
        for (int n = 0; n < 4; ++n)
          acc[m][n] = __builtin_amdgcn_mfma_f32_16x16x32_bf16(
              af[m][kk], bfv[n][kk], acc[m][n], 0, 0, 0);
    cur ^= 1;
  }
#undef STAGE

  // D layout (verified m89/m91): col = lane&15, row = (lane>>4)*4 + e
  #pragma unroll
  for (int m = 0; m < 4; ++m) {
    const int row0 = bm + wM * 64 + m * 16 + g * 4;
    #pragma unroll
    for (int n = 0; n < 4; ++n) {
      const int col = bn + wN * 64 + n * 16 + r;
      const float bv = bias[col];
      #pragma unroll
      for (int e = 0; e < 4; ++e) {
        float v = acc[m][n][e] + bv;
        if (EPI == 1) v = (v > 15.f) ? v : log1pf(__expf(v));
        C[(size_t)(row0 + e) * N + col] = v;
      }
    }
  }
}

// ---------------------------------------------------------------------------
// depthwise causal conv (width 4) + bias + SiLU, slab version.
// Block = 16 rows x 512 channels. f32 out row-major coalesced; bf16 FG out
// drained from an LDS slab with rr-minor mapping (fully coalesced).
__global__ __launch_bounds__(256) void conv_silu_kernel(
    const float* __restrict__ xz, const float* __restrict__ cw,
    const float* __restrict__ cb, float* __restrict__ xh,
    short* __restrict__ xhbf) {
  __shared__ short slab[16][528];          // stride 1056B = 16B-aligned
  const int tid = threadIdx.x;
  const int c0 = blockIdx.x * 512;
  const int r0 = blockIdx.y * 16;
  const int b  = r0 >> 11;
  const int t0 = r0 & (NL - 1);
  const float* zbase = xz + ((size_t)b * NL) * (2 * NDI);

  #pragma unroll
  for (int u = 0; u < 4; ++u) {
    int unit = u * 256 + tid;              // 1024 = 16 rows x 64 chunks
    int rr = unit >> 6, cc = unit & 63;
    int t = t0 + rr, c = c0 + cc * 8;
    float acc[8];
    #pragma unroll
    for (int e = 0; e < 8; ++e) acc[e] = cb[c + e];
    #pragma unroll
    for (int k = 0; k < NDC; ++k) {
      int tt = t - (NDC - 1) + k;
      if (tt >= 0) {
        const float* rp = zbase + (size_t)tt * (2 * NDI) + c;
        #pragma unroll
        for (int e = 0; e < 8; ++e) acc[e] += cw[(c + e) * NDC + k] * rp[e];
      }
    }
    float* xo = xh + (size_t)(r0 + rr) * NDI + c;
    #pragma unroll
    for (int e = 0; e < 8; ++e) {
      float s = acc[e] / (1.f + __expf(-acc[e]));
      xo[e] = s;
      slab[rr][cc * 8 + e] = f2bf(s);
    }
  }
  __syncthreads();
  short* op = xhbf + (size_t)(r0 >> 4) * NDI * 16 + (size_t)(c0 >> 3) * 128;
  #pragma unroll
  for (int u = 0; u < 4; ++u) {
    int u2 = u * 256 + tid;
    int rr = u2 & 15, q = u2 >> 4;         // rr-minor -> contiguous
    *(short8*)&op[q * 128 + rr * 8] = *(short8*)&slab[rr][q * 8];
  }
}

// ---------------------------------------------------------------------------
// Bmat[row, s] = sum_c xh[row,c] * W_x[c, 16+s] + b_x[16+s]; one wave per row
__global__ __launch_bounds__(256) void bmat_kernel(
    const float* __restrict__ xh, const float* __restrict__ Wx,
    const float* __restrict__ bx, float* __restrict__ Bm) {
  const int row  = blockIdx.x * 4 + (threadIdx.x >> 6);
  const int lane = threadIdx.x & 63;
  const int s = lane & 15, q = lane >> 4;
  const float* xr = xh + (size_t)row * NDI;
  float acc = 0.f;
  for (int c = q * 512; c < (q + 1) * 512; ++c)
    acc += xr[c] * Wx[c * (2 * NDS) + NDS + s];
  acc += __shfl_xor(acc, 16);
  acc += __shfl_xor(acc, 32);
  if (lane < 16) Bm[(size_t)row * NDS + s] = acc + bx[NDS + s];
}

// ---------------------------------------------------------------------------
// scan scratch layout: [b][k][c][s] -> offset ((b*CCH+k)*NDI+c)*NDS+s
__device__ __forceinline__ size_t scoff(int b, int k, int c) {
  return (((size_t)b * CCH + k) * NDI + c) * NDS;
}

// phase 1: thread = (b, c, chunk); 16 states in registers.
__global__ __launch_bounds__(256) void scan_p1_kernel(
    const float* __restrict__ delta, const float* __restrict__ Bm,
    const float* __restrict__ xh, const float* __restrict__ A_log,
    float* __restrict__ Pbuf, float* __restrict__ Hend) {
  const int i = blockIdx.x * 256 + threadIdx.x;     // NB*CCH*NDI
  const int c = i & (NDI - 1);
  const int k = (i >> 11) & (CCH - 1);
  const int b = i >> 16;
  const int t0 = k * CLEN;

  float Av[NDS];
  #pragma unroll
  for (int s = 0; s < NDS; ++s) Av[s] = -__expf(A_log[c * NDS + s]);

  const float* dp = delta + ((size_t)(b * NL + t0)) * NDI + c;
  const float* up = xh    + ((size_t)(b * NL + t0)) * NDI + c;
  const f32x4* Bp = (const f32x4*)(Bm + ((size_t)(b * NL + t0)) * NDS);

  float h[NDS], P[NDS];
  #pragma unroll
  for (int s = 0; s < NDS; ++s) { h[s] = 0.f; P[s] = 1.f; }

  #pragma unroll 4
  for (int j = 0; j < CLEN; ++j) {
    const float d = dp[(size_t)j * NDI];
    const float u = up[(size_t)j * NDI];
    f32x4 B0 = Bp[j * 4 + 0], B1 = Bp[j * 4 + 1];
    f32x4 B2 = Bp[j * 4 + 2], B3 = Bp[j * 4 + 3];
    const float du = d * u;
    float Bv[NDS];
    #pragma unroll
    for (int e = 0; e < 4; ++e) {
      Bv[e] = B0[e]; Bv[4 + e] = B1[e]; Bv[8 + e] = B2[e]; Bv[12 + e] = B3[e];
    }
    #pragma unroll
    for (int s = 0; s < NDS; ++s) {
      float dA = __expf(d * Av[s]);
      h[s] = dA * h[s] + du * Bv[s];
      P[s] *= dA;
    }
  }

  const size_t base = scoff(b, k, c);
  #pragma unroll
  for (int q = 0; q < 4; ++q) {
    *(f32x4*)&Pbuf[base + q * 4] = (f32x4){P[q*4], P[q*4+1], P[q*4+2], P[q*4+3]};
    *(f32x4*)&Hend[base + q * 4] = (f32x4){h[q*4], h[q*4+1], h[q*4+2], h[q*4+3]};
  }
}

// ---------------------------------------------------------------------------
// phase 2: thread = (b, c, s); serial combine across the chunks.
__global__ __launch_bounds__(256) void scan_p2_kernel(
    const float* __restrict__ Pbuf, const float* __restrict__ Hend,
    float* __restrict__ Hin) {
  const int i = blockIdx.x * 256 + threadIdx.x;     // 65536
  const int s = i & (NDS - 1);
  const int c = (i >> 4) & (NDI - 1);
  const int b = i >> 15;
  const size_t step = (size_t)NDI * NDS;
  const size_t base = scoff(b, 0, c) + s;
  float h = 0.f;
  #pragma unroll 8
  for (int k = 0; k < CCH; ++k) {
    Hin[base + (size_t)k * step] = h;
    h = Hend[base + (size_t)k * step] + Pbuf[base + (size_t)k * step] * h;
  }
}

// ---------------------------------------------------------------------------
// phase 3 + merge: rescan from h_in; y = (sum_s h + u*D) * silu(z);
// LDS slab-transpose -> FG bf16 output, rr-minor drain (coalesced).
__global__ __launch_bounds__(256) void scan_p3_kernel(
    const float* __restrict__ delta, const float* __restrict__ Bm,
    const float* __restrict__ xh, const float* __restrict__ A_log,
    const float* __restrict__ Hin, const float* __restrict__ Dvec,
    const float* __restrict__ xz, short* __restrict__ ybf) {
  const int tid = threadIdx.x;
  const int i = blockIdx.x * 256 + tid;
  const int c = i & (NDI - 1);
  const int k = (i >> 11) & (CCH - 1);
  const int b = i >> 16;
  const int t0 = k * CLEN;
  const int cb0 = (blockIdx.x * 256) & (NDI - 1);   // block's base channel

  __shared__ float ylds[16][257];

  float Av[NDS];
  #pragma unroll
  for (int s = 0; s < NDS; ++s) Av[s] = -__expf(A_log[c * NDS + s]);
  const float dcoef = Dvec[c];

  const float* dp = delta + ((size_t)(b * NL + t0)) * NDI + c;
  const float* up = xh    + ((size_t)(b * NL + t0)) * NDI + c;
  const f32x4* Bp = (const f32x4*)(Bm + ((size_t)(b * NL + t0)) * NDS);
  const float* zp = xz    + ((size_t)(b * NL + t0)) * (2 * NDI) + NDI + c;

  const size_t base = scoff(b, k, c);
  float h[NDS];
  #pragma unroll
  for (int s = 0; s < NDS; ++s) h[s] = Hin[base + s];

  for (int j = 0; j < CLEN; ++j) {
    const float d = dp[(size_t)j * NDI];
    const float u = up[(size_t)j * NDI];
    f32x4 B0 = Bp[j * 4 + 0], B1 = Bp[j * 4 + 1];
    f32x4 B2 = Bp[j * 4 + 2], B3 = Bp[j * 4 + 3];
    const float du = d * u;
    float Bv[NDS];
    #pragma unroll
    for (int e = 0; e < 4; ++e) {
      Bv[e] = B0[e]; Bv[4 + e] = B1[e]; Bv[8 + e] = B2[e]; Bv[12 + e] = B3[e];
    }
    #pragma unroll
    for (int s = 0; s < NDS; ++s) {
      float dA = __expf(d * Av[s]);
      h[s] = dA * h[s] + du * Bv[s];
    }
    float sum01 = 0.f, sum23 = 0.f;
    #pragma unroll
    for (int s = 0; s < 8; ++s)  sum01 += h[s];
    #pragma unroll
    for (int s = 8; s < 16; ++s) sum23 += h[s];
    float y = sum01 + sum23 + u * dcoef;
    float z = zp[(size_t)j * (2 * NDI)];
    y *= z / (1.f + __expf(-z));
    ylds[j & 15][tid] = y;

    if ((j & 15) == 15) {               // drain slab: 16 t x 256 c -> FG
      __syncthreads();
      const int jb = j - 15;
      #pragma unroll
      for (int s2 = 0; s2 < 2; ++s2) {
        int u2 = tid + 256 * s2;
        int tt = u2 & 15, q = u2 >> 4;  // rr-minor -> contiguous 16B chunks
        short8 v;
        #pragma unroll
        for (int e = 0; e < 8; ++e) v[e] = f2bf(ylds[tt][q * 8 + e]);
        int grow = b * NL + t0 + jb + tt;
        int k8 = (cb0 >> 3) + q;
        *(short8*)&ybf[fgoff(grow, k8, NDI)] = v;
      }
      __syncthreads();
    }
  }
}

// ---------------------------------------------------------------------------
extern "C" void kernel_launch(void* const* d_in, const int* in_sizes, int n_in,
                              void* d_out, int out_size, void* d_ws, size_t ws_size,
                              hipStream_t stream) {
  const float* x      = (const float*)d_in[0];
  const float* W_in   = (const float*)d_in[1];
  const float* b_in   = (const float*)d_in[2];
  const float* conv_w = (const float*)d_in[3];
  const float* conv_b = (const float*)d_in[4];
  const float* W_x    = (const float*)d_in[5];
  const float* b_x    = (const float*)d_in[6];
  const float* W_dt   = (const float*)d_in[7];
  const float* b_dt   = (const float*)d_in[8];
  const float* A_log  = (const float*)d_in[9];
  const float* Dv     = (const float*)d_in[10];
  const float* W_out  = (const float*)d_in[11];
  const float* b_out  = (const float*)d_in[12];
  float* out = (float*)d_out;

  char* w = (char*)d_ws;
  short* xbf   = (short*)(w);                  // FG 4096x1024 bf16   8.39MB
  short* WtIn  = (short*)(w + 8388608);        // FG 4096x1024 bf16   8.39MB
  short* WtDt  = (short*)(w + 16777216);       // FG 2048x2048 bf16   8.39MB
  short* WtOut = (short*)(w + 25165824);       // FG 1024x2048 bf16   4.19MB
  float* xz    = (float*)(w + 29360128);       // 4096x4096 f32      67.1MB
  float* xhf   = (float*)(w + 96468992);       // 4096x2048 f32      33.6MB
  short* xhbf  = (short*)(w + 130023424);      // FG 4096x2048 bf16  16.8MB
  float* delta = (float*)(w + 146800640);      // 4096x2048 f32      33.6MB
  float* Bm    = (float*)(w + 180355072);      // 4096x16   f32       0.26MB
  short* ybf   = (short*)(w + 214171648);      // FG 4096x2048 bf16  16.8MB
  // scan scratch aliases buffers dead by scan time (8.39MB each, CCH=32):
  float* Pbuf  = (float*)(w);                  // aliases xbf
  float* Hend  = (float*)(w + 8388608);        // aliases WtIn
  float* Hin   = (float*)(w + 16777216);       // aliases WtDt

  // 1) converts / weight transposes into FG layout
  cvt_fg_kernel<<<MROWS / 16, 256, 0, stream>>>(x, xbf);
  transpose_fg_kernel<<<dim3((2 * NDI) / 32, NDM / 64), dim3(32, 8), 0, stream>>>(
      W_in, WtIn, NDM, 2 * NDI);
  transpose_fg_kernel<<<dim3(NDI / 32, NDI / 64), dim3(32, 8), 0, stream>>>(
      W_dt, WtDt, NDI, NDI);
  transpose_fg_kernel<<<dim3(NDM / 32, NDI / 64), dim3(32, 8), 0, stream>>>(
      W_out, WtOut, NDI, NDM);

  // 2) xz = x @ W_in + b_in
  gemm_fg_kernel<0><<<dim3((2 * NDI) / 128, MROWS / 128), 256, 0, stream>>>(
      xbf, WtIn, b_in, xz, MROWS, 2 * NDI, NDM);

  // 3) depthwise conv + silu (slab; writes xhf row-major + xhbf FG)
  conv_silu_kernel<<<dim3(NDI / 512, MROWS / 16), 256, 0, stream>>>(
      xz, conv_w, conv_b, xhf, xhbf);

  // 4) Bmat = xh @ W_x[:,16:32] + b_x[16:32]
  bmat_kernel<<<MROWS / 4, 256, 0, stream>>>(xhf, W_x, b_x, Bm);

  // 5) delta = softplus(xh @ W_dt + b_dt)
  gemm_fg_kernel<1><<<dim3(NDI / 128, MROWS / 128), 256, 0, stream>>>(
      xhbf, WtDt, b_dt, delta, MROWS, NDI, NDI);

  // 6) selective scan (chunked: local scan -> chunk combine -> rescan+merge)
  scan_p1_kernel<<<(NB * NDI * CCH) / 256, 256, 0, stream>>>(
      delta, Bm, xhf, A_log, Pbuf, Hend);
  scan_p2_kernel<<<(NB * NDI * NDS) / 256, 256, 0, stream>>>(Pbuf, Hend, Hin);
  scan_p3_kernel<<<(NB * NDI * CCH) / 256, 256, 0, stream>>>(
      delta, Bm, xhf, A_log, Hin, Dv, xz, ybf);

  // 7) out = y @ W_out + b_out
  gemm_fg_kernel<0><<<dim3(NDM / 128, MROWS / 128), 256, 0, stream>>>(
      ybf, WtOut, b_out, out, MROWS, NDM, NDI);
}